// Round 4
// baseline (272.049 us; speedup 1.0000x reference)
//
#include <hip/hip_runtime.h>
#include <hip/hip_bf16.h>

// GVPDynamicProjection: N=10000, C=2, SI=128, VI=16, H=4, R=32, SH=32, VH=4
// Inputs: float32 (per reference; round-1 NaN confirmed). Output: float32
// (reference output dtype; round-2 bf16-write gave the dtype-mismatch signature).
// 5-kernel pipeline: kA (logits + q-path) -> kStats (softmax over N) ->
// kAccum (s_g/v_g) -> kSmall (k/vv GVP + attn tables) -> kAttn (attention + out)
// Round 3 was an infra failure (container); this resubmits round-2 source unchanged.

#define N_  10000
#define C_  2
#define SI_ 128
#define VI_ 16
#define H_  4
#define R_  32
#define SH_ 32
#define VH_ 4
#define NC_ (N_*C_)

typedef const float* __restrict__ fptr;

__device__ __forceinline__ float sigm(float x){ return 1.f/(1.f+__expf(-x)); }

// ---------------- ws layout (float offsets) ----------------
// lg   : [NC_][32]            logits (pre-softmax)          640000
// eqh  : [NC_][104]           per-row eq[4] @0, qh[96] @8   2080000
// sg   : [C_][32][176]        s_g(128)+v_g(48) rows         11264 (memset 0)
// st   : [64][2]              (max, denom) per (c,a)        128
// tkh  : [R_][C_][H_][3][8]   kh                            6144
// tek  : [R_][C_][H_]         ek                            256
// tvs  : [R_][C_][H_][32]     vs                            8192
// tvv  : [R_][C_][H_][4][3]   vv_                           3072
#define OFF_LG  0
#define OFF_EQH 640000
#define OFF_SG  2720000
#define OFF_ST  2731264
#define OFF_TKH 2731392
#define OFF_TEK 2737536
#define OFF_TVS 2737792
#define OFF_TVV 2745984

// ================= kernel A: per-row logits + q-path =================
// block: 256 threads, 16 rows (rc = n*2+c flattened)
__global__ __launch_bounds__(256) void kA(
    fptr s, fptr v,
    fptr wp_wh, fptr wp_ws_w, fptr wp_ws_b,
    fptr q_wh, fptr q_ws_w, fptr q_ws_b, fptr q_wv, fptr q_wsv_w, fptr q_wsv_b,
    fptr attn_wh, fptr attn_ws_w,
    float* __restrict__ lg, float* __restrict__ eqh)
{
  // XT: transposed [j][row], row-stride 20 (16B-aligned float4 at r=0/8, bank-spread)
  // j: 0..127 = s, 128..143 = vn_q, 144..159 = vn_p
  __shared__ __align__(16) float XT[160*20];
  __shared__ __align__(16) float VVs[16*48];   // v rows f32, [r][j*3+d]
  __shared__ __align__(16) float VHQ[16*48];   // vh_q, [r][d*16+j]
  __shared__ __align__(16) float SO[16*128];
  __shared__ __align__(16) float GATE[16*16];
  __shared__ __align__(16) float QV[16*48];    // qv, [r][i*3+d]

  const int tid  = threadIdx.x;
  const int row0 = blockIdx.x * 16;

  // phase 0: stage s, v
  for (int idx = tid; idx < 16*128; idx += 256){
    int r = idx >> 7, j = idx & 127;
    XT[j*20 + r] = s[(row0+r)*128 + j];
  }
  for (int idx = tid; idx < 16*48; idx += 256){
    int r = idx / 48, k = idx - r*48;
    VVs[r*48 + k] = v[(row0+r)*48 + k];
  }
  __syncthreads();

  // phase 1: vh / vn for q-path (path 0) and p-path (path 1)
  for (int t = tid; t < 512; t += 256){
    int r = t >> 5, ii = t & 31, path = ii >> 4, i = ii & 15;
    fptr wh = path ? wp_wh : q_wh;
    float h0=0.f, h1=0.f, h2=0.f;
    #pragma unroll
    for (int j = 0; j < 16; j++){
      float w = wh[j*16 + i];
      h0 = fmaf(VVs[r*48 + j*3 + 0], w, h0);
      h1 = fmaf(VVs[r*48 + j*3 + 1], w, h1);
      h2 = fmaf(VVs[r*48 + j*3 + 2], w, h2);
    }
    float vn = sqrtf(fmaxf(h0*h0 + h1*h1 + h2*h2, 1e-8f));
    if (!path){
      VHQ[r*48 +  0 + i] = h0;
      VHQ[r*48 + 16 + i] = h1;
      VHQ[r*48 + 32 + i] = h2;
      XT[(128+i)*20 + r] = vn;
    } else {
      XT[(144+i)*20 + r] = vn;
    }
  }
  __syncthreads();

  // phase 2a: so = [s, vn_q] @ q_ws_w + b   (16 rows x 128 cols)
  {
    const int col = tid & 127, rg = tid >> 7;  // rg uniform per wave
    float bqs = q_ws_b[col];
    float acc[8];
    #pragma unroll
    for (int k = 0; k < 8; k++) acc[k] = bqs;
    #pragma unroll 4
    for (int j = 0; j < 144; j++){
      float w = q_ws_w[j*128 + col];
      const float* xp = &XT[j*20 + rg*8];
      float4 x0 = *(const float4*)xp;
      float4 x1 = *(const float4*)(xp + 4);
      acc[0] = fmaf(x0.x, w, acc[0]); acc[1] = fmaf(x0.y, w, acc[1]);
      acc[2] = fmaf(x0.z, w, acc[2]); acc[3] = fmaf(x0.w, w, acc[3]);
      acc[4] = fmaf(x1.x, w, acc[4]); acc[5] = fmaf(x1.y, w, acc[5]);
      acc[6] = fmaf(x1.z, w, acc[6]); acc[7] = fmaf(x1.w, w, acc[7]);
    }
    #pragma unroll
    for (int k = 0; k < 8; k++) SO[(rg*8 + k)*128 + col] = acc[k];
  }
  // phase 2b: logits = [s, vn_p] @ wp_ws_w + b   (16 rows x 32 cols)
  {
    const int col = tid & 31, rg = tid >> 5;   // 8 groups x 2 rows
    float bp = wp_ws_b[col];
    float a0 = bp, a1 = bp;
    #pragma unroll 4
    for (int j = 0; j < 144; j++){
      int jj = (j < 128) ? j : (j + 16);       // vn_p lives at 144..159
      float w = wp_ws_w[j*32 + col];
      const float* xp = &XT[jj*20 + rg*2];
      a0 = fmaf(xp[0], w, a0);
      a1 = fmaf(xp[1], w, a1);
    }
    lg[(row0 + rg*2 + 0)*32 + col] = a0;
    lg[(row0 + rg*2 + 1)*32 + col] = a1;
  }
  __syncthreads();

  // phase 3: gate = sigmoid(sigmoid(so) @ q_wsv_w + b)    (16 rows x 16)
  {
    const int r = tid >> 4, g = tid & 15;
    float ga = q_wsv_b[g];
    for (int o = 0; o < 128; o++)
      ga = fmaf(sigm(SO[r*128 + o]), q_wsv_w[o*16 + g], ga);
    GATE[r*16 + g] = sigm(ga);
  }
  // phase 4: eq[h] = silu(so_head) . ws_q   (reads SO only, no barrier needed)
  if (tid < 64){
    const int r = tid >> 2, h = tid & 3;
    float e = 0.f;
    #pragma unroll
    for (int t = 0; t < 32; t++){
      float so = SO[r*128 + h*32 + t];
      e = fmaf(so * sigm(so), attn_ws_w[t], e);
    }
    eqh[(row0 + r)*104 + h] = e;
  }
  __syncthreads();

  // phase 5: qv = (vh_q @ q_wv)^T * gate
  for (int t = tid; t < 16*48; t += 256){
    int r = t / 48, k = t - r*48, i = k / 3, d = k - i*3;
    float acc = 0.f;
    #pragma unroll
    for (int j = 0; j < 16; j++)
      acc = fmaf(VHQ[r*48 + d*16 + j], q_wv[j*16 + i], acc);
    QV[r*48 + k] = acc * GATE[r*16 + i];
  }
  __syncthreads();

  // phase 6: qh[h][d][e] = sum_i qv[h*4+i][d] * wh_q[i][e]
  for (int t = tid; t < 16*96; t += 256){
    int r = t / 96, k = t - r*96;
    int h = k / 24, rem = k - h*24, d = rem >> 3, ee = rem & 7;
    float acc = 0.f;
    #pragma unroll
    for (int i = 0; i < 4; i++)
      acc = fmaf(QV[r*48 + (h*4 + i)*3 + d], attn_wh[i*8 + ee], acc);
    eqh[(row0 + r)*104 + 8 + k] = acc;
  }
}

// ================= kernel: softmax stats over N per (c,a) =================
__global__ __launch_bounds__(256) void kStats(const float* __restrict__ lg,
                                              float* __restrict__ st)
{
  const int q = blockIdx.x;            // c*32 + a
  const int c = q >> 5, a = q & 31;
  const int tid = threadIdx.x;
  __shared__ float red[256];

  float m = -1e30f;
  for (int n = tid; n < N_; n += 256)
    m = fmaxf(m, lg[(n*2 + c)*32 + a]);
  red[tid] = m; __syncthreads();
  for (int s2 = 128; s2 > 0; s2 >>= 1){
    if (tid < s2) red[tid] = fmaxf(red[tid], red[tid + s2]);
    __syncthreads();
  }
  const float mx = red[0];
  __syncthreads();

  float sm = 0.f;
  for (int n = tid; n < N_; n += 256)
    sm += __expf(lg[(n*2 + c)*32 + a] - mx);
  red[tid] = sm; __syncthreads();
  for (int s2 = 128; s2 > 0; s2 >>= 1){
    if (tid < s2) red[tid] += red[tid + s2];
    __syncthreads();
  }
  if (tid == 0){ st[q*2] = mx; st[q*2 + 1] = red[0]; }
}

// ================= kernel: s_g / v_g accumulation =================
// grid: 2c x 200 chunks of 50 n; thread = (a-group of 4, d-lane of 32)
#define CHUNK_ 50
__global__ __launch_bounds__(256) void kAccum(const float* __restrict__ lg,
                                              const float* __restrict__ st,
                                              fptr s, fptr v,
                                              float* __restrict__ sg)
{
  const int b = blockIdx.x, c = b & 1, chunk = b >> 1;
  const int n0 = chunk * CHUNK_;
  const int tid = threadIdx.x;
  const int ag = tid >> 5, dl = tid & 31;

  float mx[4], dn[4];
  #pragma unroll
  for (int aa = 0; aa < 4; aa++){
    int a = ag*4 + aa;
    mx[aa] = st[(c*32 + a)*2];
    dn[aa] = 1.f / st[(c*32 + a)*2 + 1];
  }
  float acc[4][6] = {};
  for (int n = n0; n < n0 + CHUNK_; n++){
    const int rc = n*2 + c;
    float pw[4];
    #pragma unroll
    for (int aa = 0; aa < 4; aa++)
      pw[aa] = __expf(lg[rc*32 + ag*4 + aa] - mx[aa]) * dn[aa];
    #pragma unroll
    for (int dd = 0; dd < 6; dd++){
      int d = dl + 32*dd;
      if (d < 176){
        float xv = (d < 128) ? s[rc*128 + d] : v[rc*48 + d - 128];
        #pragma unroll
        for (int aa = 0; aa < 4; aa++)
          acc[aa][dd] = fmaf(pw[aa], xv, acc[aa][dd]);
      }
    }
  }
  #pragma unroll
  for (int aa = 0; aa < 4; aa++)
    #pragma unroll
    for (int dd = 0; dd < 6; dd++){
      int d = dl + 32*dd;
      if (d < 176)
        atomicAdd(&sg[(c*32 + ag*4 + aa)*176 + d], acc[aa][dd]);
    }
}

// ================= kernel: k/vv GVP on s_g,v_g + attention tables =================
// grid: 64 blocks = (r, c)
__global__ __launch_bounds__(256) void kSmall(
    const float* __restrict__ sg,
    fptr k_wh, fptr k_ws_w, fptr k_ws_b, fptr k_wv, fptr k_wsv_w, fptr k_wsv_b,
    fptr vv_wh, fptr vv_ws_w, fptr vv_ws_b, fptr vv_wv, fptr vv_wsv_w, fptr vv_wsv_b,
    fptr attn_wh, fptr attn_ws_w,
    float* __restrict__ tkh, float* __restrict__ tek,
    float* __restrict__ tvs, float* __restrict__ tvv)
{
  const int b = blockIdx.x, r = b >> 1, c = b & 1;
  const int tid = threadIdx.x;
  __shared__ float X[176];
  __shared__ float VN[2][16];
  __shared__ float VH[2][48];   // [path][d*16+j]
  __shared__ float SOk[128], SOv[128];
  __shared__ float G[2][16];
  __shared__ float KV[48];      // kv, [i*3+d]

  if (tid < 176) X[tid] = sg[(c*32 + r)*176 + tid];
  __syncthreads();

  // vh / vn (path 0 = k, path 1 = vv)
  if (tid < 32){
    int path = tid >> 4, i = tid & 15;
    fptr wh = path ? vv_wh : k_wh;
    float h0=0.f, h1=0.f, h2=0.f;
    #pragma unroll
    for (int j = 0; j < 16; j++){
      float w = wh[j*16 + i];
      h0 = fmaf(X[128 + j*3 + 0], w, h0);
      h1 = fmaf(X[128 + j*3 + 1], w, h1);
      h2 = fmaf(X[128 + j*3 + 2], w, h2);
    }
    VH[path][ 0 + i] = h0; VH[path][16 + i] = h1; VH[path][32 + i] = h2;
    VN[path][i] = sqrtf(fmaxf(h0*h0 + h1*h1 + h2*h2, 1e-8f));
  }
  __syncthreads();

  // so for both paths (waves 0-1: k, waves 2-3: vv)
  {
    int path = tid >> 7, col = tid & 127;
    fptr W  = path ? vv_ws_w : k_ws_w;
    fptr Bb = path ? vv_ws_b : k_ws_b;
    float so = Bb[col];
    for (int j = 0; j < 128; j++) so = fmaf(X[j], W[j*128 + col], so);
    #pragma unroll
    for (int i = 0; i < 16; i++)  so = fmaf(VN[path][i], W[(128+i)*128 + col], so);
    (path ? SOv : SOk)[col] = so;
  }
  __syncthreads();

  // gates, ek, vs
  if (tid < 32){
    int path = tid >> 4, g = tid & 15;
    fptr Wsv = path ? vv_wsv_w : k_wsv_w;
    fptr Bsv = path ? vv_wsv_b : k_wsv_b;
    const float* SOp = path ? SOv : SOk;
    float ga = Bsv[g];
    for (int o = 0; o < 128; o++)
      ga = fmaf(sigm(SOp[o]), Wsv[o*16 + g], ga);
    G[path][g] = sigm(ga);
  } else if (tid < 36){
    int h = tid - 32;
    float e = 0.f;
    #pragma unroll
    for (int t = 0; t < 32; t++){
      float so = SOk[h*32 + t];
      e = fmaf(so * sigm(so), attn_ws_w[32 + t], e);
    }
    tek[(r*2 + c)*4 + h] = e;
  } else if (tid >= 64 && tid < 192){
    int o = tid - 64;
    float so = SOv[o];
    tvs[(r*2 + c)*128 + o] = so * sigm(so);
  }
  __syncthreads();

  // kv (path 0) and vv_ (path 1)
  if (tid < 96){
    int path = tid / 48, k = tid % 48, i = k / 3, d = k - i*3;
    fptr Wv = path ? vv_wv : k_wv;
    float vo = 0.f;
    #pragma unroll
    for (int j = 0; j < 16; j++)
      vo = fmaf(VH[path][d*16 + j], Wv[j*16 + i], vo);
    float gv = vo * G[path][i];
    if (path == 0) KV[k] = gv;
    else {
      int h = i >> 2, ii = i & 3;
      tvv[(((r*2 + c)*4 + h)*4 + ii)*3 + d] = gv;
    }
  }
  __syncthreads();

  // kh[h][d][e] = sum_i kv[h*4+i][d] * wh_k[i][e]
  if (tid < 96){
    int h = tid / 24, rem = tid % 24, d = rem >> 3, ee = rem & 7;
    float acc = 0.f;
    #pragma unroll
    for (int i = 0; i < 4; i++)
      acc = fmaf(KV[(h*4 + i)*3 + d], attn_wh[(4 + i)*8 + ee], acc);
    tkh[((r*2 + c)*4 + h)*24 + d*8 + ee] = acc;
  }
}

// ================= kernel: attention + outputs =================
// thread = (row, h); tables in LDS; VS rows padded 32->36 (bank spread)
__global__ __launch_bounds__(256, 2) void kAttn(
    const float* __restrict__ eqh,
    const float* __restrict__ tkh, const float* __restrict__ tek,
    const float* __restrict__ tvs, const float* __restrict__ tvv,
    fptr attn_ws_w, fptr attn_ws_b,
    float* __restrict__ out)
{
  __shared__ __align__(16) float KH[6144];
  __shared__ __align__(16) float EK[256];
  __shared__ __align__(16) float VS[256*36];
  __shared__ __align__(16) float VVt[3072];
  const int tid = threadIdx.x;

  for (int i = tid; i < 6144; i += 256) KH[i] = tkh[i];
  if (tid < 256) EK[tid] = tek[tid];
  for (int i = tid; i < 8192; i += 256){ int base = i >> 5, t = i & 31; VS[base*36 + t] = tvs[i]; }
  for (int i = tid; i < 3072; i += 256) VVt[i] = tvv[i];

  float wsn[8];
  #pragma unroll
  for (int ee = 0; ee < 8; ee++) wsn[ee] = attn_ws_w[64 + ee];
  const float wb = attn_ws_b[0];
  __syncthreads();

  const int row = blockIdx.x*64 + (tid >> 2);
  const int h = tid & 3;
  if (row < NC_){
    const int c = row & 1;
    const float eq = eqh[row*104 + h];
    float qh[24];
    const float4* qp = (const float4*)&eqh[row*104 + 8 + h*24];
    #pragma unroll
    for (int k = 0; k < 6; k++){
      float4 t4 = qp[k];
      qh[k*4+0] = t4.x; qh[k*4+1] = t4.y; qh[k*4+2] = t4.z; qh[k*4+3] = t4.w;
    }
    float e[32];
    float em = -1e30f;
    #pragma unroll
    for (int r = 0; r < 32; r++){
      const int base = (r*2 + c)*4 + h;
      const float* khp = &KH[base*24];
      float en = 0.f;
      #pragma unroll
      for (int ee = 0; ee < 8; ee++){
        float a0 = qh[ee]      + khp[ee];
        float a1 = qh[8 + ee]  + khp[8 + ee];
        float a2 = qh[16 + ee] + khp[16 + ee];
        en = fmaf(sqrtf(fmaxf(a0*a0 + a1*a1 + a2*a2, 1e-8f)), wsn[ee], en);
      }
      float ev = (eq + EK[base] + en + wb) * 0.17677669529663687f; // 1/sqrt(32)
      e[r] = ev; em = fmaxf(em, ev);
    }
    float den = 0.f;
    #pragma unroll
    for (int r = 0; r < 32; r++){ e[r] = __expf(e[r] - em); den += e[r]; }
    const float inv = 1.f / den;
    float accs[32] = {};
    float accv[12] = {};
    #pragma unroll
    for (int r = 0; r < 32; r++){
      const int base = (r*2 + c)*4 + h;
      const float al = e[r] * inv;
      const float* vsp = &VS[base*36];
      #pragma unroll
      for (int t = 0; t < 32; t++) accs[t] = fmaf(al, vsp[t], accs[t]);
      const float* vvp = &VVt[base*12];
      #pragma unroll
      for (int k = 0; k < 12; k++) accv[k] = fmaf(al, vvp[k], accv[k]);
    }
    float* po = &out[row*128 + h*32];
    #pragma unroll
    for (int t = 0; t < 32; t++) po[t] = accs[t];
    float* pv = &out[NC_*128 + row*48 + h*12];
    #pragma unroll
    for (int k = 0; k < 12; k++) pv[k] = accv[k];
  }
}

extern "C" void kernel_launch(void* const* d_in, const int* in_sizes, int n_in,
                              void* d_out, int out_size, void* d_ws, size_t ws_size,
                              hipStream_t stream)
{
  fptr s        = (fptr)d_in[0];
  fptr v        = (fptr)d_in[1];
  fptr wp_wh    = (fptr)d_in[2];
  fptr wp_ws_w  = (fptr)d_in[3];
  fptr wp_ws_b  = (fptr)d_in[4];
  fptr q_wh     = (fptr)d_in[5];
  fptr q_ws_w   = (fptr)d_in[6];
  fptr q_ws_b   = (fptr)d_in[7];
  fptr q_wv     = (fptr)d_in[8];
  fptr q_wsv_w  = (fptr)d_in[9];
  fptr q_wsv_b  = (fptr)d_in[10];
  fptr k_wh     = (fptr)d_in[11];
  fptr k_ws_w   = (fptr)d_in[12];
  fptr k_ws_b   = (fptr)d_in[13];
  fptr k_wv     = (fptr)d_in[14];
  fptr k_wsv_w  = (fptr)d_in[15];
  fptr k_wsv_b  = (fptr)d_in[16];
  fptr vv_wh    = (fptr)d_in[17];
  fptr vv_ws_w  = (fptr)d_in[18];
  fptr vv_ws_b  = (fptr)d_in[19];
  fptr vv_wv    = (fptr)d_in[20];
  fptr vv_wsv_w = (fptr)d_in[21];
  fptr vv_wsv_b = (fptr)d_in[22];
  fptr attn_wh  = (fptr)d_in[23];
  fptr attn_ws_w= (fptr)d_in[24];
  fptr attn_ws_b= (fptr)d_in[25];

  float* ws  = (float*)d_ws;
  float* lg  = ws + OFF_LG;
  float* eqh = ws + OFF_EQH;
  float* sg  = ws + OFF_SG;
  float* st  = ws + OFF_ST;
  float* tkh = ws + OFF_TKH;
  float* tek = ws + OFF_TEK;
  float* tvs = ws + OFF_TVS;
  float* tvv = ws + OFF_TVV;

  hipMemsetAsync(sg, 0, 11264*sizeof(float), stream);

  kA<<<NC_/16, 256, 0, stream>>>(s, v, wp_wh, wp_ws_w, wp_ws_b,
                                 q_wh, q_ws_w, q_ws_b, q_wv, q_wsv_w, q_wsv_b,
                                 attn_wh, attn_ws_w, lg, eqh);
  kStats<<<64, 256, 0, stream>>>(lg, st);
  kAccum<<<2*(N_/CHUNK_), 256, 0, stream>>>(lg, st, s, v, sg);
  kSmall<<<64, 256, 0, stream>>>(sg,
                                 k_wh, k_ws_w, k_ws_b, k_wv, k_wsv_w, k_wsv_b,
                                 vv_wh, vv_ws_w, vv_ws_b, vv_wv, vv_wsv_w, vv_wsv_b,
                                 attn_wh, attn_ws_w, tkh, tek, tvs, tvv);
  kAttn<<<(NC_ + 63)/64, 256, 0, stream>>>(eqh, tkh, tek, tvs, tvv,
                                           attn_ws_w, attn_ws_b, (float*)d_out);
}

// Round 6
// 253.160 us; speedup vs baseline: 1.0746x; 1.0746x over previous
//
#include <hip/hip_runtime.h>
#include <hip/hip_bf16.h>

// GVPDynamicProjection: N=10000, C=2, SI=128, VI=16, H=4, R=32, SH=32, VH=4
// Inputs/outputs: float32. R5/R6 changes vs R4 (272 us, kA=65 us, ~207 us hidden
// in sub-59us dispatches):
//  - lg stored TRANSPOSED [C*32][N] so kStats/kAccum reads are coalesced/broadcast
//    (was: 256B-stride gather, 64 lines/wave-load)
//  - kA: sigm(so)/silu(so) computed ONCE from registers (was 16x redundant sigm
//    in the gate GEMV); SIG aliases dead XT LDS region
//  - kAttn: 512-thread blocks (128 rows) -> 16 waves/CU vs 8 at same 73KB LDS
// (R5 submission hit an infra failure; this is the identical source, resubmitted.)

#define N_  10000
#define C_  2
#define SI_ 128
#define VI_ 16
#define H_  4
#define R_  32
#define SH_ 32
#define VH_ 4
#define NC_ (N_*C_)

typedef const float* __restrict__ fptr;

__device__ __forceinline__ float sigm(float x){ return 1.f/(1.f+__expf(-x)); }

// ---------------- ws layout (float offsets) ----------------
// lg   : [C_*32][N_]          logits TRANSPOSED             640000
// eqh  : [NC_][104]           per-row eq[4] @0, qh[96] @8   2080000
// sg   : [C_][32][176]        s_g(128)+v_g(48) rows         11264 (memset 0)
// st   : [64][2]              (max, denom) per (c,a)        128
// tkh  : [R_][C_][H_][3][8]   kh                            6144
// tek  : [R_][C_][H_]         ek                            256
// tvs  : [R_][C_][H_][32]     vs                            8192
// tvv  : [R_][C_][H_][4][3]   vv_                           3072
#define OFF_LG  0
#define OFF_EQH 640000
#define OFF_SG  2720000
#define OFF_ST  2731264
#define OFF_TKH 2731392
#define OFF_TEK 2737536
#define OFF_TVS 2737792
#define OFF_TVV 2745984

// ================= kernel A: per-row logits + q-path =================
// block: 256 threads, 16 rows (rc = n*2+c flattened); row0 = blk*16 (8 n, 2 c)
__global__ __launch_bounds__(256) void kA(
    fptr s, fptr v,
    fptr wp_wh, fptr wp_ws_w, fptr wp_ws_b,
    fptr q_wh, fptr q_ws_w, fptr q_ws_b, fptr q_wv, fptr q_wsv_w, fptr q_wsv_b,
    fptr attn_wh, fptr attn_ws_w,
    float* __restrict__ lg, float* __restrict__ eqh)
{
  // ARENA: phase 0-2 = XT transposed [j][row], stride 20 (16B-aligned float4)
  //        j: 0..127 = s, 128..143 = vn_q, 144..159 = vn_p
  //        phase 3+ = SIG [16][128] (sigm(so)), aliases dead XT
  __shared__ __align__(16) float ARENA[160*20];
  __shared__ __align__(16) float VVs[16*48];   // v rows f32, [r][j*3+d]
  __shared__ __align__(16) float VHQ[16*48];   // vh_q, [r][d*16+j]
  __shared__ __align__(16) float SO[16*128];   // holds silu(so) after phase 2
  __shared__ __align__(16) float GATE[16*16];
  __shared__ __align__(16) float QV[16*48];    // qv, [r][i*3+d]
  float* const XT  = ARENA;
  float* const SIG = ARENA;

  const int tid  = threadIdx.x;
  const int row0 = blockIdx.x * 16;

  // phase 0: stage s, v (global-coalesced; 8-way LDS write alias ~1k cyc, accepted)
  for (int idx = tid; idx < 16*128; idx += 256){
    int r = idx >> 7, j = idx & 127;
    XT[j*20 + r] = s[(row0+r)*128 + j];
  }
  for (int idx = tid; idx < 16*48; idx += 256){
    int r = idx / 48, k = idx - r*48;
    VVs[r*48 + k] = v[(row0+r)*48 + k];
  }
  __syncthreads();

  // phase 1: vh / vn for q-path (path 0) and p-path (path 1)
  for (int t = tid; t < 512; t += 256){
    int r = t >> 5, ii = t & 31, path = ii >> 4, i = ii & 15;
    fptr wh = path ? wp_wh : q_wh;
    float h0=0.f, h1=0.f, h2=0.f;
    #pragma unroll
    for (int j = 0; j < 16; j++){
      float w = wh[j*16 + i];
      h0 = fmaf(VVs[r*48 + j*3 + 0], w, h0);
      h1 = fmaf(VVs[r*48 + j*3 + 1], w, h1);
      h2 = fmaf(VVs[r*48 + j*3 + 2], w, h2);
    }
    float vn = sqrtf(fmaxf(h0*h0 + h1*h1 + h2*h2, 1e-8f));
    if (!path){
      VHQ[r*48 +  0 + i] = h0;
      VHQ[r*48 + 16 + i] = h1;
      VHQ[r*48 + 32 + i] = h2;
      XT[(128+i)*20 + r] = vn;
    } else {
      XT[(144+i)*20 + r] = vn;
    }
  }
  __syncthreads();

  // phase 2a: so = [s, vn_q] @ q_ws_w + b   (16 rows x 128 cols), acc stays live
  const int colA = tid & 127, rgA = tid >> 7;
  float acc[8];
  {
    float bqs = q_ws_b[colA];
    #pragma unroll
    for (int k = 0; k < 8; k++) acc[k] = bqs;
    #pragma unroll 4
    for (int j = 0; j < 144; j++){
      float w = q_ws_w[j*128 + colA];
      const float* xp = &XT[j*20 + rgA*8];
      float4 x0 = *(const float4*)xp;
      float4 x1 = *(const float4*)(xp + 4);
      acc[0] = fmaf(x0.x, w, acc[0]); acc[1] = fmaf(x0.y, w, acc[1]);
      acc[2] = fmaf(x0.z, w, acc[2]); acc[3] = fmaf(x0.w, w, acc[3]);
      acc[4] = fmaf(x1.x, w, acc[4]); acc[5] = fmaf(x1.y, w, acc[5]);
      acc[6] = fmaf(x1.z, w, acc[6]); acc[7] = fmaf(x1.w, w, acc[7]);
    }
  }
  // phase 2b: logits = [s, vn_p] @ wp_ws_w + b, stored TRANSPOSED lg[(c*32+a)][n]
  {
    const int col = tid & 31, rg = tid >> 5;   // 8 groups x 1 n (c=0 and c=1)
    float bp = wp_ws_b[col];
    float a0 = bp, a1 = bp;
    #pragma unroll 4
    for (int j = 0; j < 144; j++){
      int jj = (j < 128) ? j : (j + 16);       // vn_p lives at 144..159
      float w = wp_ws_w[j*32 + col];
      const float* xp = &XT[jj*20 + rg*2];
      a0 = fmaf(xp[0], w, a0);
      a1 = fmaf(xp[1], w, a1);
    }
    const int n = (row0 >> 1) + rg;            // rc=row0+rg*2 is (n, c=0)
    lg[(     col)*N_ + n] = a0;
    lg[(32 + col)*N_ + n] = a1;
  }
  __syncthreads();                             // XT dead; SIG region live

  // phase 2c: sig/silu once from registers (kills 16x-redundant sigm in phase 3)
  #pragma unroll
  for (int k = 0; k < 8; k++){
    float so = acc[k];
    float sg_ = sigm(so);
    SIG[(rgA*8 + k)*128 + colA] = sg_;
    SO [(rgA*8 + k)*128 + colA] = so * sg_;    // silu
  }
  __syncthreads();

  // phase 3: gate = sigmoid(sig_so @ q_wsv_w + b)    (16 rows x 16)
  {
    const int r = tid >> 4, g = tid & 15;
    float ga = q_wsv_b[g];
    #pragma unroll 8
    for (int o = 0; o < 128; o += 4){
      float4 s4 = *(const float4*)&SIG[r*128 + o];
      ga = fmaf(s4.x, q_wsv_w[(o+0)*16 + g], ga);
      ga = fmaf(s4.y, q_wsv_w[(o+1)*16 + g], ga);
      ga = fmaf(s4.z, q_wsv_w[(o+2)*16 + g], ga);
      ga = fmaf(s4.w, q_wsv_w[(o+3)*16 + g], ga);
    }
    GATE[r*16 + g] = sigm(ga);
  }
  // phase 4: eq[h] = silu_so_head . ws_q   (reads SO=silu, no barrier needed)
  if (tid < 64){
    const int r = tid >> 2, h = tid & 3;
    float e = 0.f;
    #pragma unroll
    for (int t = 0; t < 32; t++)
      e = fmaf(SO[r*128 + h*32 + t], attn_ws_w[t], e);
    eqh[(row0 + r)*104 + h] = e;
  }
  __syncthreads();

  // phase 5: qv = (vh_q @ q_wv)^T * gate
  for (int t = tid; t < 16*48; t += 256){
    int r = t / 48, k = t - r*48, i = k / 3, d = k - i*3;
    float a = 0.f;
    #pragma unroll
    for (int j = 0; j < 16; j++)
      a = fmaf(VHQ[r*48 + d*16 + j], q_wv[j*16 + i], a);
    QV[r*48 + k] = a * GATE[r*16 + i];
  }
  __syncthreads();

  // phase 6: qh[h][d][e] = sum_i qv[h*4+i][d] * wh_q[i][e]
  for (int t = tid; t < 16*96; t += 256){
    int r = t / 96, k = t - r*96;
    int h = k / 24, rem = k - h*24, d = rem >> 3, ee = rem & 7;
    float a = 0.f;
    #pragma unroll
    for (int i = 0; i < 4; i++)
      a = fmaf(QV[r*48 + (h*4 + i)*3 + d], attn_wh[i*8 + ee], a);
    eqh[(row0 + r)*104 + 8 + k] = a;
  }
}

// ================= kernel: softmax stats over N per (c,a) column =================
// lg is [64][N_]; reads fully coalesced now
__global__ __launch_bounds__(256) void kStats(const float* __restrict__ lg,
                                              float* __restrict__ st)
{
  const int q = blockIdx.x;
  const int tid = threadIdx.x;
  const float* col = lg + q*N_;
  __shared__ float red[256];

  float m = -1e30f;
  for (int n = tid; n < N_; n += 256) m = fmaxf(m, col[n]);
  red[tid] = m; __syncthreads();
  for (int s2 = 128; s2 > 0; s2 >>= 1){
    if (tid < s2) red[tid] = fmaxf(red[tid], red[tid + s2]);
    __syncthreads();
  }
  const float mx = red[0];
  __syncthreads();

  float sm = 0.f;
  for (int n = tid; n < N_; n += 256) sm += __expf(col[n] - mx);
  red[tid] = sm; __syncthreads();
  for (int s2 = 128; s2 > 0; s2 >>= 1){
    if (tid < s2) red[tid] += red[tid + s2];
    __syncthreads();
  }
  if (tid == 0){ st[q*2] = mx; st[q*2 + 1] = red[0]; }
}

// ================= kernel: s_g / v_g accumulation =================
// grid: 2c x 200 chunks of 50 n; thread = (a-group of 4, d-lane of 32)
#define CHUNK_ 50
__global__ __launch_bounds__(256) void kAccum(const float* __restrict__ lg,
                                              const float* __restrict__ st,
                                              fptr s, fptr v,
                                              float* __restrict__ sg)
{
  const int b = blockIdx.x, c = b & 1, chunk = b >> 1;
  const int n0 = chunk * CHUNK_;
  const int tid = threadIdx.x;
  const int ag = tid >> 5, dl = tid & 31;

  float mx[4], dn[4];
  #pragma unroll
  for (int aa = 0; aa < 4; aa++){
    int a = ag*4 + aa;
    mx[aa] = st[(c*32 + a)*2];
    dn[aa] = 1.f / st[(c*32 + a)*2 + 1];
  }
  float acc[4][6] = {};
  for (int n = n0; n < n0 + CHUNK_; n++){
    const int rc = n*2 + c;
    float pw[4];
    #pragma unroll
    for (int aa = 0; aa < 4; aa++)
      pw[aa] = __expf(lg[(c*32 + ag*4 + aa)*N_ + n] - mx[aa]) * dn[aa];  // broadcast
    #pragma unroll
    for (int dd = 0; dd < 6; dd++){
      int d = dl + 32*dd;
      if (d < 176){
        float xv = (d < 128) ? s[rc*128 + d] : v[rc*48 + d - 128];
        #pragma unroll
        for (int aa = 0; aa < 4; aa++)
          acc[aa][dd] = fmaf(pw[aa], xv, acc[aa][dd]);
      }
    }
  }
  #pragma unroll
  for (int aa = 0; aa < 4; aa++)
    #pragma unroll
    for (int dd = 0; dd < 6; dd++){
      int d = dl + 32*dd;
      if (d < 176)
        atomicAdd(&sg[(c*32 + ag*4 + aa)*176 + d], acc[aa][dd]);
    }
}

// ================= kernel: k/vv GVP on s_g,v_g + attention tables =================
// grid: 64 blocks = (r, c)
__global__ __launch_bounds__(256) void kSmall(
    const float* __restrict__ sg,
    fptr k_wh, fptr k_ws_w, fptr k_ws_b, fptr k_wv, fptr k_wsv_w, fptr k_wsv_b,
    fptr vv_wh, fptr vv_ws_w, fptr vv_ws_b, fptr vv_wv, fptr vv_wsv_w, fptr vv_wsv_b,
    fptr attn_wh, fptr attn_ws_w,
    float* __restrict__ tkh, float* __restrict__ tek,
    float* __restrict__ tvs, float* __restrict__ tvv)
{
  const int b = blockIdx.x, r = b >> 1, c = b & 1;
  const int tid = threadIdx.x;
  __shared__ float X[176];
  __shared__ float VN[2][16];
  __shared__ float VH[2][48];   // [path][d*16+j]
  __shared__ float SOk[128], SOv[128];
  __shared__ float G[2][16];
  __shared__ float KV[48];      // kv, [i*3+d]

  if (tid < 176) X[tid] = sg[(c*32 + r)*176 + tid];
  __syncthreads();

  // vh / vn (path 0 = k, path 1 = vv)
  if (tid < 32){
    int path = tid >> 4, i = tid & 15;
    fptr wh = path ? vv_wh : k_wh;
    float h0=0.f, h1=0.f, h2=0.f;
    #pragma unroll
    for (int j = 0; j < 16; j++){
      float w = wh[j*16 + i];
      h0 = fmaf(X[128 + j*3 + 0], w, h0);
      h1 = fmaf(X[128 + j*3 + 1], w, h1);
      h2 = fmaf(X[128 + j*3 + 2], w, h2);
    }
    VH[path][ 0 + i] = h0; VH[path][16 + i] = h1; VH[path][32 + i] = h2;
    VN[path][i] = sqrtf(fmaxf(h0*h0 + h1*h1 + h2*h2, 1e-8f));
  }
  __syncthreads();

  // so for both paths (waves 0-1: k, waves 2-3: vv)
  {
    int path = tid >> 7, col = tid & 127;
    fptr W  = path ? vv_ws_w : k_ws_w;
    fptr Bb = path ? vv_ws_b : k_ws_b;
    float so = Bb[col];
    for (int j = 0; j < 128; j++) so = fmaf(X[j], W[j*128 + col], so);
    #pragma unroll
    for (int i = 0; i < 16; i++)  so = fmaf(VN[path][i], W[(128+i)*128 + col], so);
    (path ? SOv : SOk)[col] = so;
  }
  __syncthreads();

  // gates, ek, vs
  if (tid < 32){
    int path = tid >> 4, g = tid & 15;
    fptr Wsv = path ? vv_wsv_w : k_wsv_w;
    fptr Bsv = path ? vv_wsv_b : k_wsv_b;
    const float* SOp = path ? SOv : SOk;
    float ga = Bsv[g];
    for (int o = 0; o < 128; o++)
      ga = fmaf(sigm(SOp[o]), Wsv[o*16 + g], ga);
    G[path][g] = sigm(ga);
  } else if (tid < 36){
    int h = tid - 32;
    float e = 0.f;
    #pragma unroll
    for (int t = 0; t < 32; t++){
      float so = SOk[h*32 + t];
      e = fmaf(so * sigm(so), attn_ws_w[32 + t], e);
    }
    tek[(r*2 + c)*4 + h] = e;
  } else if (tid >= 64 && tid < 192){
    int o = tid - 64;
    float so = SOv[o];
    tvs[(r*2 + c)*128 + o] = so * sigm(so);
  }
  __syncthreads();

  // kv (path 0) and vv_ (path 1)
  if (tid < 96){
    int path = tid / 48, k = tid % 48, i = k / 3, d = k - i*3;
    fptr Wv = path ? vv_wv : k_wv;
    float vo = 0.f;
    #pragma unroll
    for (int j = 0; j < 16; j++)
      vo = fmaf(VH[path][d*16 + j], Wv[j*16 + i], vo);
    float gv = vo * G[path][i];
    if (path == 0) KV[k] = gv;
    else {
      int h = i >> 2, ii = i & 3;
      tvv[(((r*2 + c)*4 + h)*4 + ii)*3 + d] = gv;
    }
  }
  __syncthreads();

  // kh[h][d][e] = sum_i kv[h*4+i][d] * wh_k[i][e]
  if (tid < 96){
    int h = tid / 24, rem = tid % 24, d = rem >> 3, ee = rem & 7;
    float a = 0.f;
    #pragma unroll
    for (int i = 0; i < 4; i++)
      a = fmaf(KV[(h*4 + i)*3 + d], attn_wh[(4 + i)*8 + ee], a);
    tkh[((r*2 + c)*4 + h)*24 + d*8 + ee] = a;
  }
}

// ================= kernel: attention + outputs =================
// 512 threads = 128 rows x 4 heads; tables in LDS (73KB -> 2 blocks/CU, 16 waves)
__global__ __launch_bounds__(512) void kAttn(
    const float* __restrict__ eqh,
    const float* __restrict__ tkh, const float* __restrict__ tek,
    const float* __restrict__ tvs, const float* __restrict__ tvv,
    fptr attn_ws_w, fptr attn_ws_b,
    float* __restrict__ out)
{
  __shared__ __align__(16) float KH[6144];
  __shared__ __align__(16) float EK[256];
  __shared__ __align__(16) float VS[256*36];   // rows padded 32->36 (bank spread)
  __shared__ __align__(16) float VVt[3072];
  const int tid = threadIdx.x;

  for (int i = tid; i < 6144; i += 512) KH[i] = tkh[i];
  if (tid < 256) EK[tid] = tek[tid];
  for (int i = tid; i < 8192; i += 512){ int base = i >> 5, t = i & 31; VS[base*36 + t] = tvs[i]; }
  for (int i = tid; i < 3072; i += 512) VVt[i] = tvv[i];

  float wsn[8];
  #pragma unroll
  for (int ee = 0; ee < 8; ee++) wsn[ee] = attn_ws_w[64 + ee];
  const float wb = attn_ws_b[0];
  __syncthreads();

  const int row = blockIdx.x*128 + (tid >> 2);
  const int h = tid & 3;
  if (row < NC_){
    const int c = row & 1;
    const float eq = eqh[row*104 + h];
    float qh[24];
    const float4* qp = (const float4*)&eqh[row*104 + 8 + h*24];
    #pragma unroll
    for (int k = 0; k < 6; k++){
      float4 t4 = qp[k];
      qh[k*4+0] = t4.x; qh[k*4+1] = t4.y; qh[k*4+2] = t4.z; qh[k*4+3] = t4.w;
    }
    float e[32];
    float em = -1e30f;
    #pragma unroll
    for (int r = 0; r < 32; r++){
      const int base = (r*2 + c)*4 + h;
      const float* khp = &KH[base*24];
      float en = 0.f;
      #pragma unroll
      for (int ee = 0; ee < 8; ee++){
        float a0 = qh[ee]      + khp[ee];
        float a1 = qh[8 + ee]  + khp[8 + ee];
        float a2 = qh[16 + ee] + khp[16 + ee];
        en = fmaf(sqrtf(fmaxf(a0*a0 + a1*a1 + a2*a2, 1e-8f)), wsn[ee], en);
      }
      float ev = (eq + EK[base] + en + wb) * 0.17677669529663687f; // 1/sqrt(32)
      e[r] = ev; em = fmaxf(em, ev);
    }
    float den = 0.f;
    #pragma unroll
    for (int r = 0; r < 32; r++){ e[r] = __expf(e[r] - em); den += e[r]; }
    const float inv = 1.f / den;
    float accs[32] = {};
    float accv[12] = {};
    #pragma unroll
    for (int r = 0; r < 32; r++){
      const int base = (r*2 + c)*4 + h;
      const float al = e[r] * inv;
      const float* vsp = &VS[base*36];
      #pragma unroll
      for (int t = 0; t < 32; t++) accs[t] = fmaf(al, vsp[t], accs[t]);
      const float* vvp = &VVt[base*12];
      #pragma unroll
      for (int k = 0; k < 12; k++) accv[k] = fmaf(al, vvp[k], accv[k]);
    }
    float* po = &out[row*128 + h*32];
    #pragma unroll
    for (int t = 0; t < 32; t++) po[t] = accs[t];
    float* pv = &out[NC_*128 + row*48 + h*12];
    #pragma unroll
    for (int k = 0; k < 12; k++) pv[k] = accv[k];
  }
}

extern "C" void kernel_launch(void* const* d_in, const int* in_sizes, int n_in,
                              void* d_out, int out_size, void* d_ws, size_t ws_size,
                              hipStream_t stream)
{
  fptr s        = (fptr)d_in[0];
  fptr v        = (fptr)d_in[1];
  fptr wp_wh    = (fptr)d_in[2];
  fptr wp_ws_w  = (fptr)d_in[3];
  fptr wp_ws_b  = (fptr)d_in[4];
  fptr q_wh     = (fptr)d_in[5];
  fptr q_ws_w   = (fptr)d_in[6];
  fptr q_ws_b   = (fptr)d_in[7];
  fptr q_wv     = (fptr)d_in[8];
  fptr q_wsv_w  = (fptr)d_in[9];
  fptr q_wsv_b  = (fptr)d_in[10];
  fptr k_wh     = (fptr)d_in[11];
  fptr k_ws_w   = (fptr)d_in[12];
  fptr k_ws_b   = (fptr)d_in[13];
  fptr k_wv     = (fptr)d_in[14];
  fptr k_wsv_w  = (fptr)d_in[15];
  fptr k_wsv_b  = (fptr)d_in[16];
  fptr vv_wh    = (fptr)d_in[17];
  fptr vv_ws_w  = (fptr)d_in[18];
  fptr vv_ws_b  = (fptr)d_in[19];
  fptr vv_wv    = (fptr)d_in[20];
  fptr vv_wsv_w = (fptr)d_in[21];
  fptr vv_wsv_b = (fptr)d_in[22];
  fptr attn_wh  = (fptr)d_in[23];
  fptr attn_ws_w= (fptr)d_in[24];
  fptr attn_ws_b= (fptr)d_in[25];

  float* ws  = (float*)d_ws;
  float* lg  = ws + OFF_LG;
  float* eqh = ws + OFF_EQH;
  float* sg  = ws + OFF_SG;
  float* st  = ws + OFF_ST;
  float* tkh = ws + OFF_TKH;
  float* tek = ws + OFF_TEK;
  float* tvs = ws + OFF_TVS;
  float* tvv = ws + OFF_TVV;

  hipMemsetAsync(sg, 0, 11264*sizeof(float), stream);

  kA<<<NC_/16, 256, 0, stream>>>(s, v, wp_wh, wp_ws_w, wp_ws_b,
                                 q_wh, q_ws_w, q_ws_b, q_wv, q_wsv_w, q_wsv_b,
                                 attn_wh, attn_ws_w, lg, eqh);
  kStats<<<64, 256, 0, stream>>>(lg, st);
  kAccum<<<2*(N_/CHUNK_), 256, 0, stream>>>(lg, st, s, v, sg);
  kSmall<<<64, 256, 0, stream>>>(sg,
                                 k_wh, k_ws_w, k_ws_b, k_wv, k_wsv_w, k_wsv_b,
                                 vv_wh, vv_ws_w, vv_ws_b, vv_wv, vv_wsv_w, vv_wsv_b,
                                 attn_wh, attn_ws_w, tkh, tek, tvs, tvv);
  kAttn<<<(NC_ + 127)/128, 512, 0, stream>>>(eqh, tkh, tek, tvs, tvv,
                                             attn_ws_w, attn_ws_b, (float*)d_out);
}